// Round 15
// baseline (245.923 us; speedup 1.0000x reference)
//
#include <hip/hip_runtime.h>

#define NN 10000
#define NE 160000
#define TT 2
#define SS 2
#define HH 64
#define ZZ 32
#define KK 4
#define NIN 4

typedef short bf16x8 __attribute__((ext_vector_type(8)));
typedef float f32x4 __attribute__((ext_vector_type(4)));

// fp32 -> bf16 (RNE)
__device__ __forceinline__ unsigned short f2b(float x) {
    unsigned u = __float_as_uint(x);
    u += 0x7fffu + ((u >> 16) & 1u);
    return (unsigned short)(u >> 16);
}
__device__ __forceinline__ float bf2f(unsigned short u) {
    return __uint_as_float(((unsigned)u) << 16);
}

// leaky(dot(zG_row(bf16 pairs), qf[32]))
__device__ __forceinline__ float edge_score(const unsigned* __restrict__ zp,
                                            const float* __restrict__ qf) {
    float a = 0.f;
#pragma unroll
    for (int j = 0; j < 16; ++j) {
        unsigned u = zp[j];
        a += __uint_as_float(u << 16) * qf[2*j]
           + __uint_as_float(u & 0xffff0000u) * qf[2*j+1];
    }
    return a > 0.f ? a : 0.01f*a;
}

// P0: merged prep. blocks 0..15: attnM (MT[k][j][i], transposed). block 16: fold.
// blocks 17+: bf16 conversions + xt init + deg count.
__global__ __launch_bounds__(256) void k_prep(
    const float* __restrict__ Ws, const float* __restrict__ Wd,
    const float* __restrict__ F2w1, const float* __restrict__ xw,
    const float* __restrict__ xb, const float* __restrict__ F2w2,
    const float* __restrict__ F1w1, const float* __restrict__ F1w2,
    const float* __restrict__ ow1, const float* __restrict__ ow2,
    const float* __restrict__ zA, const float* __restrict__ zG,
    const float* __restrict__ inputs, const int* __restrict__ dst,
    float* __restrict__ MT, float* __restrict__ G1, float* __restrict__ G2,
    float* __restrict__ c1, float* __restrict__ c2,
    unsigned short* __restrict__ W2b, unsigned short* __restrict__ F1w1b,
    unsigned short* __restrict__ F1w2b, unsigned short* __restrict__ ow1b,
    unsigned short* __restrict__ ow2b, unsigned short* __restrict__ zAb,
    unsigned short* __restrict__ zGb, float* __restrict__ xt,
    int* __restrict__ deg_i)
{
    int b = blockIdx.x;
    int tid = threadIdx.x;
    if (b < 16) {
        int o = b*256 + tid;              // 4096 outputs
        int j = o & 31, i = (o >> 5) & 31, k = o >> 10;
        float acc = 0.0f;
        for (int h = 0; h < HH; ++h)
            acc += Ws[(k*HH + h)*ZZ + i] * Wd[(k*HH + h)*ZZ + j];
        MT[(k*ZZ + j)*ZZ + i] = acc;
    } else if (b == 16) {
        int h = tid >> 2, i = tid & 3;
        float a1 = 0.f, a2 = 0.f;
        for (int j = 0; j < HH; ++j) {
            float x = xw[j*NIN + i];
            a1 += F2w1[h*128 + j] * x;
            a2 += F2w1[h*128 + 64 + j] * x;
        }
        G1[h*4 + i] = a1;
        G2[h*4 + i] = a2;
        if (i == 0) {
            float b1 = 0.f, b2 = 0.f;
            for (int j = 0; j < HH; ++j) {
                float bb = xb[j];
                b1 += F2w1[h*128 + j] * bb;
                b2 += F2w1[h*128 + 64 + j] * bb;
            }
            c1[h] = b1; c2[h] = b2;
        }
    } else {
        int t = (b - 17)*256 + tid;
        if (t < NN*SS*ZZ) { zAb[t] = f2b(zA[t]); zGb[t] = f2b(zG[t]); }
        if (t < HH*HH)    { W2b[t] = f2b(F2w2[t]); F1w2b[t] = f2b(F1w2[t]); }
        if (t < HH*KK*HH) F1w1b[t] = f2b(F1w1[t]);
        if (t < HH*(HH+ZZ)) ow1b[t] = f2b(ow1[t]);
        if (t < 4*HH)     ow2b[t] = f2b(ow2[t]);
        if (t < NN*SS*NIN) {
            int i = t & 3;
            int n = t >> 3;
            xt[t] = inputs[n*(TT*NIN) + i];
        }
        if (t < NE) atomicAdd(deg_i + dst[t], 1);
    }
}

// C2: exclusive scan of deg_i -> offsets[0..NN], cursor copy (1 block, Hillis-Steele)
__global__ void k_scan(const int* __restrict__ deg_i, int* __restrict__ offsets,
                       int* __restrict__ cursor) {
    __shared__ int buf0[1024], buf1[1024];
    int tidx = threadIdx.x;
    const int CH = (NN + 1023) / 1024;   // 10
    int b0 = tidx * CH;
    int sum = 0;
    for (int i = 0; i < CH; ++i) { int idx = b0 + i; if (idx < NN) sum += deg_i[idx]; }
    buf0[tidx] = sum;
    __syncthreads();
    int* s = buf0; int* d = buf1;
    for (int off = 1; off < 1024; off <<= 1) {
        d[tidx] = s[tidx] + (tidx >= off ? s[tidx - off] : 0);
        __syncthreads();
        int* tmp = s; s = d; d = tmp;
    }
    int run = s[tidx] - sum;
    for (int i = 0; i < CH; ++i) {
        int idx = b0 + i;
        if (idx < NN) { offsets[idx] = run; cursor[idx] = run; run += deg_i[idx]; }
    }
    if (tidx == 0) offsets[NN] = NE;
}

// C3: scatter src node ids into dst-sorted position order
__global__ void k_scatter(const int* __restrict__ src, const int* __restrict__ dst,
                          int* __restrict__ cursor, int* __restrict__ src_by_pos) {
    int e = blockIdx.x * blockDim.x + threadIdx.x;
    if (e >= NE) return;
    int pos = atomicAdd(cursor + dst[e], 1);
    src_by_pos[pos] = src[e];
}

// Fused attention + step-0 aggregation. 4 waves/block, one (n,s) item per wave.
// Per-wave LDS regions; no block barriers (wave-internal LDS ordering).
__global__ __launch_bounds__(256) void k_attn_agg0(
    const float* __restrict__ MT, const float* __restrict__ zG,
    const unsigned short* __restrict__ zGb, const int* __restrict__ src_by_pos,
    const int* __restrict__ offsets, const float* __restrict__ xt,
    const float* __restrict__ G1, const float* __restrict__ G2,
    const float* __restrict__ c1, const float* __restrict__ c2,
    float* alpha, unsigned short* __restrict__ agg_b)
{
    __shared__ float sq[4][128];          // per-wave qd flat [k*32+i]
    __shared__ float alpha_s[4][64][4];   // per-wave alpha cache, first 64 edges
    int tid = threadIdx.x;
    int w = tid >> 6, l = tid & 63;
    int item = blockIdx.x*4 + w;
    int n = item >> 1, s = item & 1;
    int i = l >> 2, k = l & 3;
    int r0 = offsets[n], r1 = offsets[n+1];

    // ---- phase 0: qd in-wave (2 entries per lane) ----
    {
        int i0 = l & 31;
        int k0 = l >> 5;         // 0..1
        int k1 = k0 + 2;         // 2..3
        const float* zg = zG + item*ZZ;
        float acc0 = 0.f, acc1 = 0.f;
#pragma unroll
        for (int j = 0; j < ZZ; ++j) {
            float z = zg[j];
            acc0 += MT[(k0*ZZ + j)*ZZ + i0] * z;
            acc1 += MT[(k1*ZZ + j)*ZZ + i0] * z;
        }
        sq[w][k0*ZZ + i0] = acc0;
        sq[w][k1*ZZ + i0] = acc1;
    }
    float qf[32];
#pragma unroll
    for (int j = 0; j < 32; ++j) qf[j] = sq[w][k*ZZ + j];

    // ---- phase 1: scores -> alpha ----
    float E[8];
    float mx = -1e30f;
    int nit = 0;
    for (int idx = r0 + i; idx < r1; idx += 16, ++nit) {
        int sn = src_by_pos[idx];
        float e = edge_score((const unsigned*)(zGb + (sn*SS + s)*ZZ), qf);
        if (nit < 8) E[nit] = e;
        mx = fmaxf(mx, e);
    }
#pragma unroll
    for (int off = 4; off < 64; off <<= 1) mx = fmaxf(mx, __shfl_xor(mx, off));
    float sum = 0.f;
    nit = 0;
    for (int idx = r0 + i; idx < r1; idx += 16, ++nit) {
        float e = (nit < 8) ? E[nit]
                : edge_score((const unsigned*)(zGb + (src_by_pos[idx]*SS + s)*ZZ), qf);
        sum += __expf(e - mx);
    }
#pragma unroll
    for (int off = 4; off < 64; off <<= 1) sum += __shfl_xor(sum, off);
    int deg = r1 - r0;
    float dd = (float)(deg > 1 ? deg : 1);
    float inv = sum > 0.f ? 1.f/(sum*dd) : 0.f;
    nit = 0;
    for (int idx = r0 + i; idx < r1; idx += 16, ++nit) {
        float e = (nit < 8) ? E[nit]
                : edge_score((const unsigned*)(zGb + (src_by_pos[idx]*SS + s)*ZZ), qf);
        float a = __expf(e - mx) * inv;
        alpha[(idx*2 + s)*4 + k] = a;
        int jo = idx - r0;
        if (jo < 64) alpha_s[w][jo][k] = a;
    }

    // ---- phase 2: step-0 aggregation (lane = h), unrolled x4 ----
    int h = l;
    const float4 g1 = *(const float4*)(G1 + h*4);
    const float4 g2 = *(const float4*)(G2 + h*4);
    const float4 xd = *(const float4*)(xt + item*4);
    float p2 = c2[h] + xd.x*g2.x + xd.y*g2.y + xd.z*g2.z + xd.w*g2.w;
    float c1h = c1[h];
    float a0 = 0.f, a1 = 0.f, a2 = 0.f, a3 = 0.f;
    int jo = 0;
    for (; jo + 4 <= deg; jo += 4) {
        int sn0 = src_by_pos[r0 + jo];
        int sn1 = src_by_pos[r0 + jo + 1];
        int sn2 = src_by_pos[r0 + jo + 2];
        int sn3 = src_by_pos[r0 + jo + 3];
        float4 x0 = *(const float4*)(xt + (sn0*SS + s)*NIN);
        float4 x1 = *(const float4*)(xt + (sn1*SS + s)*NIN);
        float4 x2 = *(const float4*)(xt + (sn2*SS + s)*NIN);
        float4 x3 = *(const float4*)(xt + (sn3*SS + s)*NIN);
        float4 w0 = (jo+0 < 64) ? *(const float4*)(&alpha_s[w][jo+0][0])
                                : *(const float4*)(alpha + ((r0+jo+0)*2 + s)*4);
        float4 w1 = (jo+1 < 64) ? *(const float4*)(&alpha_s[w][jo+1][0])
                                : *(const float4*)(alpha + ((r0+jo+1)*2 + s)*4);
        float4 w2 = (jo+2 < 64) ? *(const float4*)(&alpha_s[w][jo+2][0])
                                : *(const float4*)(alpha + ((r0+jo+2)*2 + s)*4);
        float4 w3 = (jo+3 < 64) ? *(const float4*)(&alpha_s[w][jo+3][0])
                                : *(const float4*)(alpha + ((r0+jo+3)*2 + s)*4);
        float p, hd;
        p = c1h + x0.x*g1.x + x0.y*g1.y + x0.z*g1.z + x0.w*g1.w;
        hd = p + p2; hd = hd > 0.f ? hd : 0.f;
        a0 += w0.x*hd; a1 += w0.y*hd; a2 += w0.z*hd; a3 += w0.w*hd;
        p = c1h + x1.x*g1.x + x1.y*g1.y + x1.z*g1.z + x1.w*g1.w;
        hd = p + p2; hd = hd > 0.f ? hd : 0.f;
        a0 += w1.x*hd; a1 += w1.y*hd; a2 += w1.z*hd; a3 += w1.w*hd;
        p = c1h + x2.x*g1.x + x2.y*g1.y + x2.z*g1.z + x2.w*g1.w;
        hd = p + p2; hd = hd > 0.f ? hd : 0.f;
        a0 += w2.x*hd; a1 += w2.y*hd; a2 += w2.z*hd; a3 += w2.w*hd;
        p = c1h + x3.x*g1.x + x3.y*g1.y + x3.z*g1.z + x3.w*g1.w;
        hd = p + p2; hd = hd > 0.f ? hd : 0.f;
        a0 += w3.x*hd; a1 += w3.y*hd; a2 += w3.z*hd; a3 += w3.w*hd;
    }
    for (; jo < deg; ++jo) {
        int sn = src_by_pos[r0 + jo];
        float4 x0 = *(const float4*)(xt + (sn*SS + s)*NIN);
        float4 w4 = (jo < 64) ? *(const float4*)(&alpha_s[w][jo][0])
                              : *(const float4*)(alpha + ((r0+jo)*2 + s)*4);
        float p = c1h + x0.x*g1.x + x0.y*g1.y + x0.z*g1.z + x0.w*g1.w;
        float hd = p + p2; hd = hd > 0.f ? hd : 0.f;
        a0 += w4.x*hd; a1 += w4.y*hd; a2 += w4.z*hd; a3 += w4.w*hd;
    }
    agg_b[item*256 +       h] = f2b(a0);
    agg_b[item*256 + 64  + h] = f2b(a1);
    agg_b[item*256 + 128 + h] = f2b(a2);
    agg_b[item*256 + 192 + h] = f2b(a3);
}

// B2: fused xenc + edge layer-1 + aggregation (step 1). 4 waves/block,
// one item per wave. Edge loop unrolled x4.
__global__ __launch_bounds__(256) void k_agg2(
    const float* __restrict__ xt, const float* __restrict__ G1,
    const float* __restrict__ G2, const float* __restrict__ c1,
    const float* __restrict__ c2, const int* __restrict__ src_by_pos,
    const int* __restrict__ offsets, const float* __restrict__ alpha,
    unsigned short* __restrict__ agg_b)
{
    int tid = threadIdx.x;
    int w = tid >> 6, h = tid & 63;
    int item = blockIdx.x*4 + w;
    int n = item >> 1, s = item & 1;
    int r0 = offsets[n], r1 = offsets[n+1];
    const float4 g1 = *(const float4*)(G1 + h*4);
    const float4 g2 = *(const float4*)(G2 + h*4);
    const float4 xd = *(const float4*)(xt + item*4);
    float p2 = c2[h] + xd.x*g2.x + xd.y*g2.y + xd.z*g2.z + xd.w*g2.w;
    float c1h = c1[h];
    float a0 = 0.f, a1 = 0.f, a2 = 0.f, a3 = 0.f;
    int idx = r0;
    for (; idx + 4 <= r1; idx += 4) {
        int sn0 = src_by_pos[idx];
        int sn1 = src_by_pos[idx+1];
        int sn2 = src_by_pos[idx+2];
        int sn3 = src_by_pos[idx+3];
        float4 x0 = *(const float4*)(xt + (sn0*SS + s)*NIN);
        float4 x1 = *(const float4*)(xt + (sn1*SS + s)*NIN);
        float4 x2 = *(const float4*)(xt + (sn2*SS + s)*NIN);
        float4 x3 = *(const float4*)(xt + (sn3*SS + s)*NIN);
        float4 w0 = *(const float4*)(alpha + ((idx+0)*2 + s)*4);
        float4 w1 = *(const float4*)(alpha + ((idx+1)*2 + s)*4);
        float4 w2 = *(const float4*)(alpha + ((idx+2)*2 + s)*4);
        float4 w3 = *(const float4*)(alpha + ((idx+3)*2 + s)*4);
        float p, hd;
        p = c1h + x0.x*g1.x + x0.y*g1.y + x0.z*g1.z + x0.w*g1.w;
        hd = p + p2; hd = hd > 0.f ? hd : 0.f;
        a0 += w0.x*hd; a1 += w0.y*hd; a2 += w0.z*hd; a3 += w0.w*hd;
        p = c1h + x1.x*g1.x + x1.y*g1.y + x1.z*g1.z + x1.w*g1.w;
        hd = p + p2; hd = hd > 0.f ? hd : 0.f;
        a0 += w1.x*hd; a1 += w1.y*hd; a2 += w1.z*hd; a3 += w1.w*hd;
        p = c1h + x2.x*g1.x + x2.y*g1.y + x2.z*g1.z + x2.w*g1.w;
        hd = p + p2; hd = hd > 0.f ? hd : 0.f;
        a0 += w2.x*hd; a1 += w2.y*hd; a2 += w2.z*hd; a3 += w2.w*hd;
        p = c1h + x3.x*g1.x + x3.y*g1.y + x3.z*g1.z + x3.w*g1.w;
        hd = p + p2; hd = hd > 0.f ? hd : 0.f;
        a0 += w3.x*hd; a1 += w3.y*hd; a2 += w3.z*hd; a3 += w3.w*hd;
    }
    for (; idx < r1; ++idx) {
        int sn = src_by_pos[idx];
        float4 x0 = *(const float4*)(xt + (sn*SS + s)*NIN);
        float4 w0 = *(const float4*)(alpha + (idx*2 + s)*4);
        float p = c1h + x0.x*g1.x + x0.y*g1.y + x0.z*g1.z + x0.w*g1.w;
        float hd = p + p2; hd = hd > 0.f ? hd : 0.f;
        a0 += w0.x*hd; a1 += w0.y*hd; a2 += w0.z*hd; a3 += w0.w*hd;
    }
    agg_b[item*256 +       h] = f2b(a0);
    agg_b[item*256 + 64  + h] = f2b(a1);
    agg_b[item*256 + 128 + h] = f2b(a2);
    agg_b[item*256 + 192 + h] = f2b(a3);
}

// B3: GEMM0 (agg@W2^T block-diag per head) + chained node GEMMs.
// 4 waves/block, 16 items/wave. Per-wave LDS only, no barrier.
__global__ __launch_bounds__(256) void k_node_mfma(
    const unsigned short* __restrict__ agg_b, const unsigned short* __restrict__ zAb,
    const unsigned short* __restrict__ W2b,
    const unsigned short* __restrict__ F1w1b, const unsigned short* __restrict__ F1w2b,
    const unsigned short* __restrict__ ow1b, const unsigned short* __restrict__ ow2b,
    const float* __restrict__ ob1, const float* __restrict__ ob2,
    float* __restrict__ xt, float* __restrict__ out, int tstep)
{
    __shared__ unsigned short res_s[4][16*264];
    __shared__ unsigned short hid_s[4][16*72];
    __shared__ unsigned short hcat_s[4][16*104];
    int tid = threadIdx.x;
    int w = tid >> 6, l = tid & 63, l15 = l & 15, qq = l >> 4;

    bf16x8 w2f[2][4], b2f[2][4], o1f[3][4], bo2[2];
#pragma unroll
    for (int nb = 0; nb < 4; ++nb) {
        int n = nb*16 + l15;
#pragma unroll
        for (int kb = 0; kb < 2; ++kb) {
            w2f[kb][nb] = *(const bf16x8*)(W2b  + n*64 + kb*32 + qq*8);
            b2f[kb][nb] = *(const bf16x8*)(F1w2b + n*64 + kb*32 + qq*8);
        }
#pragma unroll
        for (int kb = 0; kb < 3; ++kb)
            o1f[kb][nb] = *(const bf16x8*)(ow1b + n*96 + kb*32 + qq*8);
    }
#pragma unroll
    for (int kb = 0; kb < 2; ++kb) {
        if (l15 < 4) bo2[kb] = *(const bf16x8*)(ow2b + l15*64 + kb*32 + qq*8);
        else {
            bf16x8 z;
#pragma unroll
            for (int j = 0; j < 8; ++j) z[j] = 0;
            bo2[kb] = z;
        }
    }
    float b1v[4];
#pragma unroll
    for (int nb = 0; nb < 4; ++nb) b1v[nb] = ob1[nb*16 + l15];
    float b2v = (l15 < 4) ? ob2[l15] : 0.0f;

    int itemBase = blockIdx.x*64 + w*16;
    if (itemBase >= NN*SS) return;

    *(uint4*)(&hcat_s[w][l15*104 + 64 + qq*8]) =
        *(const uint4*)(zAb + (itemBase + l15)*ZZ + qq*8);

    // GEMM0: res[item, k*64+h'] = sum_h agg[item,k*64+h] * W2[h'][h]
#pragma unroll
    for (int k = 0; k < 4; ++k) {
        f32x4 acc0[4];
#pragma unroll
        for (int nb = 0; nb < 4; ++nb) acc0[nb] = (f32x4)(0.0f);
#pragma unroll
        for (int kb = 0; kb < 2; ++kb) {
            bf16x8 af = *(const bf16x8*)(agg_b + (itemBase + l15)*256 + k*64 + kb*32 + qq*8);
#pragma unroll
            for (int nb = 0; nb < 4; ++nb)
                acc0[nb] = __builtin_amdgcn_mfma_f32_16x16x32_bf16(af, w2f[kb][nb], acc0[nb], 0, 0, 0);
        }
#pragma unroll
        for (int nb = 0; nb < 4; ++nb)
#pragma unroll
            for (int r = 0; r < 4; ++r)
                res_s[w][(qq*4 + r)*264 + k*64 + nb*16 + l15] = f2b(acc0[nb][r]);
    }

    // GEMM1: res[16x256] @ F1w1^T[256x64], relu
    f32x4 acc[4];
#pragma unroll
    for (int nb = 0; nb < 4; ++nb) acc[nb] = (f32x4)(0.0f);
#pragma unroll
    for (int kb = 0; kb < 8; ++kb) {
        bf16x8 af = *(const bf16x8*)(&res_s[w][l15*264 + kb*32 + qq*8]);
#pragma unroll
        for (int nb = 0; nb < 4; ++nb) {
            bf16x8 bf = *(const bf16x8*)(F1w1b + (nb*16 + l15)*256 + kb*32 + qq*8);
            acc[nb] = __builtin_amdgcn_mfma_f32_16x16x32_bf16(af, bf, acc[nb], 0, 0, 0);
        }
    }
#pragma unroll
    for (int nb = 0; nb < 4; ++nb)
#pragma unroll
        for (int r = 0; r < 4; ++r) {
            float v = acc[nb][r];
            hid_s[w][(qq*4 + r)*72 + nb*16 + l15] = f2b(v > 0.0f ? v : 0.0f);
        }

    // GEMM2: hid[16x64] @ F1w2^T[64x64] -> deltax -> hcat cols 0..63
    f32x4 acc2[4];
#pragma unroll
    for (int nb = 0; nb < 4; ++nb) acc2[nb] = (f32x4)(0.0f);
#pragma unroll
    for (int kb = 0; kb < 2; ++kb) {
        bf16x8 af = *(const bf16x8*)(&hid_s[w][l15*72 + kb*32 + qq*8]);
#pragma unroll
        for (int nb = 0; nb < 4; ++nb)
            acc2[nb] = __builtin_amdgcn_mfma_f32_16x16x32_bf16(af, b2f[kb][nb], acc2[nb], 0, 0, 0);
    }
#pragma unroll
    for (int nb = 0; nb < 4; ++nb)
#pragma unroll
        for (int r = 0; r < 4; ++r)
            hcat_s[w][(qq*4 + r)*104 + nb*16 + l15] = f2b(acc2[nb][r]);

    // GEMM3: hcat[16x96] @ ow1^T[96x64] + b1, relu -> hid_s
    f32x4 acc3[4];
#pragma unroll
    for (int nb = 0; nb < 4; ++nb) acc3[nb] = (f32x4)(0.0f);
#pragma unroll
    for (int kb = 0; kb < 3; ++kb) {
        bf16x8 af = *(const bf16x8*)(&hcat_s[w][l15*104 + kb*32 + qq*8]);
#pragma unroll
        for (int nb = 0; nb < 4; ++nb)
            acc3[nb] = __builtin_amdgcn_mfma_f32_16x16x32_bf16(af, o1f[kb][nb], acc3[nb], 0, 0, 0);
    }
#pragma unroll
    for (int nb = 0; nb < 4; ++nb)
#pragma unroll
        for (int r = 0; r < 4; ++r) {
            float v = acc3[nb][r] + b1v[nb];
            hid_s[w][(qq*4 + r)*72 + nb*16 + l15] = f2b(v > 0.0f ? v : 0.0f);
        }

    // GEMM4: hid[16x64] @ ow2^T[64x4(pad16)] + b2
    f32x4 acc4 = (f32x4)(0.0f);
#pragma unroll
    for (int kb = 0; kb < 2; ++kb) {
        bf16x8 af = *(const bf16x8*)(&hid_s[w][l15*72 + kb*32 + qq*8]);
        acc4 = __builtin_amdgcn_mfma_f32_16x16x32_bf16(af, bo2[kb], acc4, 0, 0, 0);
    }
    if (l15 < 4) {
#pragma unroll
        for (int r = 0; r < 4; ++r) {
            int item = itemBase + qq*4 + r;
            float nx = xt[item*4 + l15] + acc4[r] + b2v;
            xt[item*4 + l15] = nx;
            int n = item >> 1, s = item & 1;
            out[((n*TT + tstep)*SS + s)*4 + l15] = nx;
        }
    }
}

extern "C" void kernel_launch(void* const* d_in, const int* in_sizes, int n_in,
                              void* d_out, int out_size, void* d_ws, size_t ws_size,
                              hipStream_t stream) {
    const float* inputs = (const float*)d_in[0];
    const float* zA     = (const float*)d_in[1];
    const float* zG     = (const float*)d_in[2];
    const int*   src    = (const int*)d_in[3];
    const int*   dst    = (const int*)d_in[4];
    const float* Ws     = (const float*)d_in[5];
    const float* Wd     = (const float*)d_in[6];
    const float* F2w1   = (const float*)d_in[7];
    const float* F2w2   = (const float*)d_in[8];
    const float* F1w1   = (const float*)d_in[9];
    const float* F1w2   = (const float*)d_in[10];
    const float* xw     = (const float*)d_in[11];
    const float* xb     = (const float*)d_in[12];
    const float* ow1    = (const float*)d_in[13];
    const float* ob1    = (const float*)d_in[14];
    const float* ow2    = (const float*)d_in[15];
    const float* ob2    = (const float*)d_in[16];
    float* out = (float*)d_out;

    // ---- workspace carve (units: floats) ----
    float*          base        = (float*)d_ws;
    float*          MT          = base;                              // 4,096
    float*          alpha       = base + 4096;                       // 1,280,000
    int*            deg_i       = (int*)(base + 1284096);            // 10,000 (zeroed)
    int*            offsets     = (int*)(base + 1294096);            // 10,016
    int*            cursor      = (int*)(base + 1304112);            // 10,000
    int*            src_by_pos  = (int*)(base + 1314112);            // 160,000
    float*          xt          = base + 1474112;                    // 80,000
    float*          G1f         = base + 1554112;                    // 256
    float*          G2f         = base + 1554368;                    // 256
    float*          c1f         = base + 1554624;                    // 64
    float*          c2f         = base + 1554688;                    // 64 (pad to 1,554,816)
    unsigned short* W2b         = (unsigned short*)(base + 1554816); // 4,096 ush
    unsigned short* F1w1b       = (unsigned short*)(base + 1556864); // 16,384 ush
    unsigned short* F1w2b       = (unsigned short*)(base + 1565056); // 4,096 ush
    unsigned short* ow1b        = (unsigned short*)(base + 1567104); // 6,144 ush
    unsigned short* ow2b        = (unsigned short*)(base + 1570176); // 256 ush
    unsigned short* zAb         = (unsigned short*)(base + 1570304); // 640,000 ush
    unsigned short* zGb         = (unsigned short*)(base + 1890304); // 640,000 ush
    unsigned short* agg_b       = (unsigned short*)(base + 2210304); // 5,120,000 ush
    // total 4,770,304 floats = 19.1 MB

    hipMemsetAsync(deg_i, 0, 10000u * 4u, stream);

    // ---- attention phase (once) ----
    const int CONVB = (NN*SS*ZZ + 255)/256;   // 2500
    k_prep<<<17 + CONVB, 256, 0, stream>>>(Ws, Wd, F2w1, xw, xb, F2w2, F1w1, F1w2,
                                           ow1, ow2, zA, zG, inputs, dst,
                                           MT, G1f, G2f, c1f, c2f,
                                           W2b, F1w1b, F1w2b, ow1b, ow2b,
                                           zAb, zGb, xt, deg_i);
    k_scan<<<1, 1024, 0, stream>>>(deg_i, offsets, cursor);
    k_scatter<<<(NE + 255)/256, 256, 0, stream>>>(src, dst, cursor, src_by_pos);

    // ---- step 0 (attention fused with aggregation) ----
    k_attn_agg0<<<NN*SS/4, 256, 0, stream>>>(MT, zG, zGb, src_by_pos, offsets, xt,
                                             G1f, G2f, c1f, c2f, alpha, agg_b);
    k_node_mfma<<<(NN*SS + 63)/64, 256, 0, stream>>>(agg_b, zAb, W2b, F1w1b, F1w2b,
                                                     ow1b, ow2b, ob1, ob2, xt, out, 0);
    // ---- step 1 ----
    k_agg2<<<NN*SS/4, 256, 0, stream>>>(xt, G1f, G2f, c1f, c2f,
                                        src_by_pos, offsets, alpha, agg_b);
    k_node_mfma<<<(NN*SS + 63)/64, 256, 0, stream>>>(agg_b, zAb, W2b, F1w1b, F1w2b,
                                                     ow1b, ow2b, ob1, ob2, xt, out, 1);
}

// Round 16
// 226.831 us; speedup vs baseline: 1.0842x; 1.0842x over previous
//
#include <hip/hip_runtime.h>

#define NN 10000
#define NE 160000
#define TT 2
#define SS 2
#define HH 64
#define ZZ 32
#define KK 4
#define NIN 4

typedef short bf16x8 __attribute__((ext_vector_type(8)));
typedef float f32x4 __attribute__((ext_vector_type(4)));

// fp32 -> bf16 (RNE)
__device__ __forceinline__ unsigned short f2b(float x) {
    unsigned u = __float_as_uint(x);
    u += 0x7fffu + ((u >> 16) & 1u);
    return (unsigned short)(u >> 16);
}
__device__ __forceinline__ float bf2f(unsigned short u) {
    return __uint_as_float(((unsigned)u) << 16);
}

// leaky(dot(zG_row(bf16 pairs), qf[32]))
__device__ __forceinline__ float edge_score(const unsigned* __restrict__ zp,
                                            const float* __restrict__ qf) {
    float a = 0.f;
#pragma unroll
    for (int j = 0; j < 16; ++j) {
        unsigned u = zp[j];
        a += __uint_as_float(u << 16) * qf[2*j]
           + __uint_as_float(u & 0xffff0000u) * qf[2*j+1];
    }
    return a > 0.f ? a : 0.01f*a;
}

// P0: merged prep. blocks 0..15: attnM (MT[k][j][i], transposed). block 16: fold.
// blocks 17+: bf16 conversions + xt init + deg count.
__global__ __launch_bounds__(256) void k_prep(
    const float* __restrict__ Ws, const float* __restrict__ Wd,
    const float* __restrict__ F2w1, const float* __restrict__ xw,
    const float* __restrict__ xb, const float* __restrict__ F2w2,
    const float* __restrict__ F1w1, const float* __restrict__ F1w2,
    const float* __restrict__ ow1, const float* __restrict__ ow2,
    const float* __restrict__ zA, const float* __restrict__ zG,
    const float* __restrict__ inputs, const int* __restrict__ dst,
    float* __restrict__ MT, float* __restrict__ G1, float* __restrict__ G2,
    float* __restrict__ c1, float* __restrict__ c2,
    unsigned short* __restrict__ W2b, unsigned short* __restrict__ F1w1b,
    unsigned short* __restrict__ F1w2b, unsigned short* __restrict__ ow1b,
    unsigned short* __restrict__ ow2b, unsigned short* __restrict__ zAb,
    unsigned short* __restrict__ zGb, float* __restrict__ xt,
    int* __restrict__ deg_i)
{
    int b = blockIdx.x;
    int tid = threadIdx.x;
    if (b < 16) {
        int o = b*256 + tid;              // 4096 outputs
        int j = o & 31, i = (o >> 5) & 31, k = o >> 10;
        float acc = 0.0f;
        for (int h = 0; h < HH; ++h)
            acc += Ws[(k*HH + h)*ZZ + i] * Wd[(k*HH + h)*ZZ + j];
        MT[(k*ZZ + j)*ZZ + i] = acc;
    } else if (b == 16) {
        int h = tid >> 2, i = tid & 3;
        float a1 = 0.f, a2 = 0.f;
        for (int j = 0; j < HH; ++j) {
            float x = xw[j*NIN + i];
            a1 += F2w1[h*128 + j] * x;
            a2 += F2w1[h*128 + 64 + j] * x;
        }
        G1[h*4 + i] = a1;
        G2[h*4 + i] = a2;
        if (i == 0) {
            float b1 = 0.f, b2 = 0.f;
            for (int j = 0; j < HH; ++j) {
                float bb = xb[j];
                b1 += F2w1[h*128 + j] * bb;
                b2 += F2w1[h*128 + 64 + j] * bb;
            }
            c1[h] = b1; c2[h] = b2;
        }
    } else {
        int t = (b - 17)*256 + tid;
        if (t < NN*SS*ZZ) { zAb[t] = f2b(zA[t]); zGb[t] = f2b(zG[t]); }
        if (t < HH*HH)    { W2b[t] = f2b(F2w2[t]); F1w2b[t] = f2b(F1w2[t]); }
        if (t < HH*KK*HH) F1w1b[t] = f2b(F1w1[t]);
        if (t < HH*(HH+ZZ)) ow1b[t] = f2b(ow1[t]);
        if (t < 4*HH)     ow2b[t] = f2b(ow2[t]);
        if (t < NN*SS*NIN) {
            int i = t & 3;
            int n = t >> 3;
            xt[t] = inputs[n*(TT*NIN) + i];
        }
        if (t < NE) atomicAdd(deg_i + dst[t], 1);
    }
}

// C2: exclusive scan of deg_i -> offsets[0..NN], cursor copy (1 block, Hillis-Steele)
__global__ void k_scan(const int* __restrict__ deg_i, int* __restrict__ offsets,
                       int* __restrict__ cursor) {
    __shared__ int buf0[1024], buf1[1024];
    int tidx = threadIdx.x;
    const int CH = (NN + 1023) / 1024;   // 10
    int b0 = tidx * CH;
    int sum = 0;
    for (int i = 0; i < CH; ++i) { int idx = b0 + i; if (idx < NN) sum += deg_i[idx]; }
    buf0[tidx] = sum;
    __syncthreads();
    int* s = buf0; int* d = buf1;
    for (int off = 1; off < 1024; off <<= 1) {
        d[tidx] = s[tidx] + (tidx >= off ? s[tidx - off] : 0);
        __syncthreads();
        int* tmp = s; s = d; d = tmp;
    }
    int run = s[tidx] - sum;
    for (int i = 0; i < CH; ++i) {
        int idx = b0 + i;
        if (idx < NN) { offsets[idx] = run; cursor[idx] = run; run += deg_i[idx]; }
    }
    if (tidx == 0) offsets[NN] = NE;
}

// C3: scatter src node ids into dst-sorted position order
__global__ void k_scatter(const int* __restrict__ src, const int* __restrict__ dst,
                          int* __restrict__ cursor, int* __restrict__ src_by_pos) {
    int e = blockIdx.x * blockDim.x + threadIdx.x;
    if (e >= NE) return;
    int pos = atomicAdd(cursor + dst[e], 1);
    src_by_pos[pos] = src[e];
}

// Fused attention + step-0 aggregation. One 64-thread block per (n,s) item
// (independent small blocks win for degree-skewed loops — R15 post-mortem).
// Phase 0: qd in-block from MT + fp32 zG. Phase 1: scores -> alpha.
// Phase 2: aggregation (lane = h), unrolled x4.
__global__ __launch_bounds__(64) void k_attn_agg0(
    const float* __restrict__ MT, const float* __restrict__ zG,
    const unsigned short* __restrict__ zGb, const int* __restrict__ src_by_pos,
    const int* __restrict__ offsets, const float* __restrict__ xt,
    const float* __restrict__ G1, const float* __restrict__ G2,
    const float* __restrict__ c1, const float* __restrict__ c2,
    float* alpha, unsigned short* __restrict__ agg_b)
{
    __shared__ float sq[128];          // qd flat [k*32+i]
    __shared__ float alpha_s[64][4];   // alpha cache, first 64 edges
    int item = blockIdx.x;
    int n = item >> 1, s = item & 1;
    int l = threadIdx.x;
    int i = l >> 2, k = l & 3;
    int r0 = offsets[n], r1 = offsets[n+1];

    // ---- phase 0: qd in-block (2 entries per lane) ----
    {
        int i0 = l & 31;
        int k0 = l >> 5;         // 0..1
        int k1 = k0 + 2;         // 2..3
        const float* zg = zG + item*ZZ;
        float acc0 = 0.f, acc1 = 0.f;
#pragma unroll
        for (int j = 0; j < ZZ; ++j) {
            float z = zg[j];
            acc0 += MT[(k0*ZZ + j)*ZZ + i0] * z;
            acc1 += MT[(k1*ZZ + j)*ZZ + i0] * z;
        }
        sq[k0*ZZ + i0] = acc0;
        sq[k1*ZZ + i0] = acc1;
    }
    __syncthreads();
    float qf[32];
#pragma unroll
    for (int j = 0; j < 32; ++j) qf[j] = sq[k*ZZ + j];

    // ---- phase 1: scores -> alpha ----
    float E[8];
    float mx = -1e30f;
    int nit = 0;
    for (int idx = r0 + i; idx < r1; idx += 16, ++nit) {
        int sn = src_by_pos[idx];
        float e = edge_score((const unsigned*)(zGb + (sn*SS + s)*ZZ), qf);
        if (nit < 8) E[nit] = e;
        mx = fmaxf(mx, e);
    }
#pragma unroll
    for (int off = 4; off < 64; off <<= 1) mx = fmaxf(mx, __shfl_xor(mx, off));
    float sum = 0.f;
    nit = 0;
    for (int idx = r0 + i; idx < r1; idx += 16, ++nit) {
        float e = (nit < 8) ? E[nit]
                : edge_score((const unsigned*)(zGb + (src_by_pos[idx]*SS + s)*ZZ), qf);
        sum += __expf(e - mx);
    }
#pragma unroll
    for (int off = 4; off < 64; off <<= 1) sum += __shfl_xor(sum, off);
    int deg = r1 - r0;
    float dd = (float)(deg > 1 ? deg : 1);
    float inv = sum > 0.f ? 1.f/(sum*dd) : 0.f;
    nit = 0;
    for (int idx = r0 + i; idx < r1; idx += 16, ++nit) {
        float e = (nit < 8) ? E[nit]
                : edge_score((const unsigned*)(zGb + (src_by_pos[idx]*SS + s)*ZZ), qf);
        float a = __expf(e - mx) * inv;
        alpha[(idx*2 + s)*4 + k] = a;
        int jo = idx - r0;
        if (jo < 64) alpha_s[jo][k] = a;
    }
    __syncthreads();

    // ---- phase 2: step-0 aggregation (lane = h), unrolled x4 ----
    int h = l;
    const float4 g1 = *(const float4*)(G1 + h*4);
    const float4 g2 = *(const float4*)(G2 + h*4);
    const float4 xd = *(const float4*)(xt + item*4);
    float p2 = c2[h] + xd.x*g2.x + xd.y*g2.y + xd.z*g2.z + xd.w*g2.w;
    float c1h = c1[h];
    float a0 = 0.f, a1 = 0.f, a2 = 0.f, a3 = 0.f;
    int jo = 0;
    for (; jo + 4 <= deg; jo += 4) {
        int sn0 = src_by_pos[r0 + jo];
        int sn1 = src_by_pos[r0 + jo + 1];
        int sn2 = src_by_pos[r0 + jo + 2];
        int sn3 = src_by_pos[r0 + jo + 3];
        float4 x0 = *(const float4*)(xt + (sn0*SS + s)*NIN);
        float4 x1 = *(const float4*)(xt + (sn1*SS + s)*NIN);
        float4 x2 = *(const float4*)(xt + (sn2*SS + s)*NIN);
        float4 x3 = *(const float4*)(xt + (sn3*SS + s)*NIN);
        float4 w0 = (jo+0 < 64) ? *(const float4*)(&alpha_s[jo+0][0])
                                : *(const float4*)(alpha + ((r0+jo+0)*2 + s)*4);
        float4 w1 = (jo+1 < 64) ? *(const float4*)(&alpha_s[jo+1][0])
                                : *(const float4*)(alpha + ((r0+jo+1)*2 + s)*4);
        float4 w2 = (jo+2 < 64) ? *(const float4*)(&alpha_s[jo+2][0])
                                : *(const float4*)(alpha + ((r0+jo+2)*2 + s)*4);
        float4 w3 = (jo+3 < 64) ? *(const float4*)(&alpha_s[jo+3][0])
                                : *(const float4*)(alpha + ((r0+jo+3)*2 + s)*4);
        float p, hd;
        p = c1h + x0.x*g1.x + x0.y*g1.y + x0.z*g1.z + x0.w*g1.w;
        hd = p + p2; hd = hd > 0.f ? hd : 0.f;
        a0 += w0.x*hd; a1 += w0.y*hd; a2 += w0.z*hd; a3 += w0.w*hd;
        p = c1h + x1.x*g1.x + x1.y*g1.y + x1.z*g1.z + x1.w*g1.w;
        hd = p + p2; hd = hd > 0.f ? hd : 0.f;
        a0 += w1.x*hd; a1 += w1.y*hd; a2 += w1.z*hd; a3 += w1.w*hd;
        p = c1h + x2.x*g1.x + x2.y*g1.y + x2.z*g1.z + x2.w*g1.w;
        hd = p + p2; hd = hd > 0.f ? hd : 0.f;
        a0 += w2.x*hd; a1 += w2.y*hd; a2 += w2.z*hd; a3 += w2.w*hd;
        p = c1h + x3.x*g1.x + x3.y*g1.y + x3.z*g1.z + x3.w*g1.w;
        hd = p + p2; hd = hd > 0.f ? hd : 0.f;
        a0 += w3.x*hd; a1 += w3.y*hd; a2 += w3.z*hd; a3 += w3.w*hd;
    }
    for (; jo < deg; ++jo) {
        int sn = src_by_pos[r0 + jo];
        float4 x0 = *(const float4*)(xt + (sn*SS + s)*NIN);
        float4 w4 = (jo < 64) ? *(const float4*)(&alpha_s[jo][0])
                              : *(const float4*)(alpha + ((r0+jo)*2 + s)*4);
        float p = c1h + x0.x*g1.x + x0.y*g1.y + x0.z*g1.z + x0.w*g1.w;
        float hd = p + p2; hd = hd > 0.f ? hd : 0.f;
        a0 += w4.x*hd; a1 += w4.y*hd; a2 += w4.z*hd; a3 += w4.w*hd;
    }
    agg_b[item*256 +       h] = f2b(a0);
    agg_b[item*256 + 64  + h] = f2b(a1);
    agg_b[item*256 + 128 + h] = f2b(a2);
    agg_b[item*256 + 192 + h] = f2b(a3);
}

// B2: fused xenc + edge layer-1 + aggregation (step 1). One 64-thread block
// per item. Edge loop unrolled x4.
__global__ __launch_bounds__(64) void k_agg2(
    const float* __restrict__ xt, const float* __restrict__ G1,
    const float* __restrict__ G2, const float* __restrict__ c1,
    const float* __restrict__ c2, const int* __restrict__ src_by_pos,
    const int* __restrict__ offsets, const float* __restrict__ alpha,
    unsigned short* __restrict__ agg_b)
{
    int item = blockIdx.x;
    int n = item >> 1, s = item & 1;
    int h = threadIdx.x;
    int r0 = offsets[n], r1 = offsets[n+1];
    const float4 g1 = *(const float4*)(G1 + h*4);
    const float4 g2 = *(const float4*)(G2 + h*4);
    const float4 xd = *(const float4*)(xt + item*4);
    float p2 = c2[h] + xd.x*g2.x + xd.y*g2.y + xd.z*g2.z + xd.w*g2.w;
    float c1h = c1[h];
    float a0 = 0.f, a1 = 0.f, a2 = 0.f, a3 = 0.f;
    int idx = r0;
    for (; idx + 4 <= r1; idx += 4) {
        int sn0 = src_by_pos[idx];
        int sn1 = src_by_pos[idx+1];
        int sn2 = src_by_pos[idx+2];
        int sn3 = src_by_pos[idx+3];
        float4 x0 = *(const float4*)(xt + (sn0*SS + s)*NIN);
        float4 x1 = *(const float4*)(xt + (sn1*SS + s)*NIN);
        float4 x2 = *(const float4*)(xt + (sn2*SS + s)*NIN);
        float4 x3 = *(const float4*)(xt + (sn3*SS + s)*NIN);
        float4 w0 = *(const float4*)(alpha + ((idx+0)*2 + s)*4);
        float4 w1 = *(const float4*)(alpha + ((idx+1)*2 + s)*4);
        float4 w2 = *(const float4*)(alpha + ((idx+2)*2 + s)*4);
        float4 w3 = *(const float4*)(alpha + ((idx+3)*2 + s)*4);
        float p, hd;
        p = c1h + x0.x*g1.x + x0.y*g1.y + x0.z*g1.z + x0.w*g1.w;
        hd = p + p2; hd = hd > 0.f ? hd : 0.f;
        a0 += w0.x*hd; a1 += w0.y*hd; a2 += w0.z*hd; a3 += w0.w*hd;
        p = c1h + x1.x*g1.x + x1.y*g1.y + x1.z*g1.z + x1.w*g1.w;
        hd = p + p2; hd = hd > 0.f ? hd : 0.f;
        a0 += w1.x*hd; a1 += w1.y*hd; a2 += w1.z*hd; a3 += w1.w*hd;
        p = c1h + x2.x*g1.x + x2.y*g1.y + x2.z*g1.z + x2.w*g1.w;
        hd = p + p2; hd = hd > 0.f ? hd : 0.f;
        a0 += w2.x*hd; a1 += w2.y*hd; a2 += w2.z*hd; a3 += w2.w*hd;
        p = c1h + x3.x*g1.x + x3.y*g1.y + x3.z*g1.z + x3.w*g1.w;
        hd = p + p2; hd = hd > 0.f ? hd : 0.f;
        a0 += w3.x*hd; a1 += w3.y*hd; a2 += w3.z*hd; a3 += w3.w*hd;
    }
    for (; idx < r1; ++idx) {
        int sn = src_by_pos[idx];
        float4 x0 = *(const float4*)(xt + (sn*SS + s)*NIN);
        float4 w0 = *(const float4*)(alpha + (idx*2 + s)*4);
        float p = c1h + x0.x*g1.x + x0.y*g1.y + x0.z*g1.z + x0.w*g1.w;
        float hd = p + p2; hd = hd > 0.f ? hd : 0.f;
        a0 += w0.x*hd; a1 += w0.y*hd; a2 += w0.z*hd; a3 += w0.w*hd;
    }
    agg_b[item*256 +       h] = f2b(a0);
    agg_b[item*256 + 64  + h] = f2b(a1);
    agg_b[item*256 + 128 + h] = f2b(a2);
    agg_b[item*256 + 192 + h] = f2b(a3);
}

// B3: GEMM0 (agg@W2^T block-diag per head) + chained node GEMMs.
// 4 waves/block, 16 items/wave. Per-wave LDS only, no barrier.
__global__ __launch_bounds__(256) void k_node_mfma(
    const unsigned short* __restrict__ agg_b, const unsigned short* __restrict__ zAb,
    const unsigned short* __restrict__ W2b,
    const unsigned short* __restrict__ F1w1b, const unsigned short* __restrict__ F1w2b,
    const unsigned short* __restrict__ ow1b, const unsigned short* __restrict__ ow2b,
    const float* __restrict__ ob1, const float* __restrict__ ob2,
    float* __restrict__ xt, float* __restrict__ out, int tstep)
{
    __shared__ unsigned short res_s[4][16*264];
    __shared__ unsigned short hid_s[4][16*72];
    __shared__ unsigned short hcat_s[4][16*104];
    int tid = threadIdx.x;
    int w = tid >> 6, l = tid & 63, l15 = l & 15, qq = l >> 4;

    bf16x8 w2f[2][4], b2f[2][4], o1f[3][4], bo2[2];
#pragma unroll
    for (int nb = 0; nb < 4; ++nb) {
        int n = nb*16 + l15;
#pragma unroll
        for (int kb = 0; kb < 2; ++kb) {
            w2f[kb][nb] = *(const bf16x8*)(W2b  + n*64 + kb*32 + qq*8);
            b2f[kb][nb] = *(const bf16x8*)(F1w2b + n*64 + kb*32 + qq*8);
        }
#pragma unroll
        for (int kb = 0; kb < 3; ++kb)
            o1f[kb][nb] = *(const bf16x8*)(ow1b + n*96 + kb*32 + qq*8);
    }
#pragma unroll
    for (int kb = 0; kb < 2; ++kb) {
        if (l15 < 4) bo2[kb] = *(const bf16x8*)(ow2b + l15*64 + kb*32 + qq*8);
        else {
            bf16x8 z;
#pragma unroll
            for (int j = 0; j < 8; ++j) z[j] = 0;
            bo2[kb] = z;
        }
    }
    float b1v[4];
#pragma unroll
    for (int nb = 0; nb < 4; ++nb) b1v[nb] = ob1[nb*16 + l15];
    float b2v = (l15 < 4) ? ob2[l15] : 0.0f;

    int itemBase = blockIdx.x*64 + w*16;
    if (itemBase >= NN*SS) return;

    *(uint4*)(&hcat_s[w][l15*104 + 64 + qq*8]) =
        *(const uint4*)(zAb + (itemBase + l15)*ZZ + qq*8);

    // GEMM0: res[item, k*64+h'] = sum_h agg[item,k*64+h] * W2[h'][h]
#pragma unroll
    for (int k = 0; k < 4; ++k) {
        f32x4 acc0[4];
#pragma unroll
        for (int nb = 0; nb < 4; ++nb) acc0[nb] = (f32x4)(0.0f);
#pragma unroll
        for (int kb = 0; kb < 2; ++kb) {
            bf16x8 af = *(const bf16x8*)(agg_b + (itemBase + l15)*256 + k*64 + kb*32 + qq*8);
#pragma unroll
            for (int nb = 0; nb < 4; ++nb)
                acc0[nb] = __builtin_amdgcn_mfma_f32_16x16x32_bf16(af, w2f[kb][nb], acc0[nb], 0, 0, 0);
        }
#pragma unroll
        for (int nb = 0; nb < 4; ++nb)
#pragma unroll
            for (int r = 0; r < 4; ++r)
                res_s[w][(qq*4 + r)*264 + k*64 + nb*16 + l15] = f2b(acc0[nb][r]);
    }

    // GEMM1: res[16x256] @ F1w1^T[256x64], relu
    f32x4 acc[4];
#pragma unroll
    for (int nb = 0; nb < 4; ++nb) acc[nb] = (f32x4)(0.0f);
#pragma unroll
    for (int kb = 0; kb < 8; ++kb) {
        bf16x8 af = *(const bf16x8*)(&res_s[w][l15*264 + kb*32 + qq*8]);
#pragma unroll
        for (int nb = 0; nb < 4; ++nb) {
            bf16x8 bf = *(const bf16x8*)(F1w1b + (nb*16 + l15)*256 + kb*32 + qq*8);
            acc[nb] = __builtin_amdgcn_mfma_f32_16x16x32_bf16(af, bf, acc[nb], 0, 0, 0);
        }
    }
#pragma unroll
    for (int nb = 0; nb < 4; ++nb)
#pragma unroll
        for (int r = 0; r < 4; ++r) {
            float v = acc[nb][r];
            hid_s[w][(qq*4 + r)*72 + nb*16 + l15] = f2b(v > 0.0f ? v : 0.0f);
        }

    // GEMM2: hid[16x64] @ F1w2^T[64x64] -> deltax -> hcat cols 0..63
    f32x4 acc2[4];
#pragma unroll
    for (int nb = 0; nb < 4; ++nb) acc2[nb] = (f32x4)(0.0f);
#pragma unroll
    for (int kb = 0; kb < 2; ++kb) {
        bf16x8 af = *(const bf16x8*)(&hid_s[w][l15*72 + kb*32 + qq*8]);
#pragma unroll
        for (int nb = 0; nb < 4; ++nb)
            acc2[nb] = __builtin_amdgcn_mfma_f32_16x16x32_bf16(af, b2f[kb][nb], acc2[nb], 0, 0, 0);
    }
#pragma unroll
    for (int nb = 0; nb < 4; ++nb)
#pragma unroll
        for (int r = 0; r < 4; ++r)
            hcat_s[w][(qq*4 + r)*104 + nb*16 + l15] = f2b(acc2[nb][r]);

    // GEMM3: hcat[16x96] @ ow1^T[96x64] + b1, relu -> hid_s
    f32x4 acc3[4];
#pragma unroll
    for (int nb = 0; nb < 4; ++nb) acc3[nb] = (f32x4)(0.0f);
#pragma unroll
    for (int kb = 0; kb < 3; ++kb) {
        bf16x8 af = *(const bf16x8*)(&hcat_s[w][l15*104 + kb*32 + qq*8]);
#pragma unroll
        for (int nb = 0; nb < 4; ++nb)
            acc3[nb] = __builtin_amdgcn_mfma_f32_16x16x32_bf16(af, o1f[kb][nb], acc3[nb], 0, 0, 0);
    }
#pragma unroll
    for (int nb = 0; nb < 4; ++nb)
#pragma unroll
        for (int r = 0; r < 4; ++r) {
            float v = acc3[nb][r] + b1v[nb];
            hid_s[w][(qq*4 + r)*72 + nb*16 + l15] = f2b(v > 0.0f ? v : 0.0f);
        }

    // GEMM4: hid[16x64] @ ow2^T[64x4(pad16)] + b2
    f32x4 acc4 = (f32x4)(0.0f);
#pragma unroll
    for (int kb = 0; kb < 2; ++kb) {
        bf16x8 af = *(const bf16x8*)(&hid_s[w][l15*72 + kb*32 + qq*8]);
        acc4 = __builtin_amdgcn_mfma_f32_16x16x32_bf16(af, bo2[kb], acc4, 0, 0, 0);
    }
    if (l15 < 4) {
#pragma unroll
        for (int r = 0; r < 4; ++r) {
            int item = itemBase + qq*4 + r;
            float nx = xt[item*4 + l15] + acc4[r] + b2v;
            xt[item*4 + l15] = nx;
            int n = item >> 1, s = item & 1;
            out[((n*TT + tstep)*SS + s)*4 + l15] = nx;
        }
    }
}

extern "C" void kernel_launch(void* const* d_in, const int* in_sizes, int n_in,
                              void* d_out, int out_size, void* d_ws, size_t ws_size,
                              hipStream_t stream) {
    const float* inputs = (const float*)d_in[0];
    const float* zA     = (const float*)d_in[1];
    const float* zG     = (const float*)d_in[2];
    const int*   src    = (const int*)d_in[3];
    const int*   dst    = (const int*)d_in[4];
    const float* Ws     = (const float*)d_in[5];
    const float* Wd     = (const float*)d_in[6];
    const float* F2w1   = (const float*)d_in[7];
    const float* F2w2   = (const float*)d_in[8];
    const float* F1w1   = (const float*)d_in[9];
    const float* F1w2   = (const float*)d_in[10];
    const float* xw     = (const float*)d_in[11];
    const float* xb     = (const float*)d_in[12];
    const float* ow1    = (const float*)d_in[13];
    const float* ob1    = (const float*)d_in[14];
    const float* ow2    = (const float*)d_in[15];
    const float* ob2    = (const float*)d_in[16];
    float* out = (float*)d_out;

    // ---- workspace carve (units: floats) ----
    float*          base        = (float*)d_ws;
    float*          MT          = base;                              // 4,096
    float*          alpha       = base + 4096;                       // 1,280,000
    int*            deg_i       = (int*)(base + 1284096);            // 10,000 (zeroed)
    int*            offsets     = (int*)(base + 1294096);            // 10,016
    int*            cursor      = (int*)(base + 1304112);            // 10,000
    int*            src_by_pos  = (int*)(base + 1314112);            // 160,000
    float*          xt          = base + 1474112;                    // 80,000
    float*          G1f         = base + 1554112;                    // 256
    float*          G2f         = base + 1554368;                    // 256
    float*          c1f         = base + 1554624;                    // 64
    float*          c2f         = base + 1554688;                    // 64 (pad to 1,554,816)
    unsigned short* W2b         = (unsigned short*)(base + 1554816); // 4,096 ush
    unsigned short* F1w1b       = (unsigned short*)(base + 1556864); // 16,384 ush
    unsigned short* F1w2b       = (unsigned short*)(base + 1565056); // 4,096 ush
    unsigned short* ow1b        = (unsigned short*)(base + 1567104); // 6,144 ush
    unsigned short* ow2b        = (unsigned short*)(base + 1570176); // 256 ush
    unsigned short* zAb         = (unsigned short*)(base + 1570304); // 640,000 ush
    unsigned short* zGb         = (unsigned short*)(base + 1890304); // 640,000 ush
    unsigned short* agg_b       = (unsigned short*)(base + 2210304); // 5,120,000 ush
    // total 4,770,304 floats = 19.1 MB

    hipMemsetAsync(deg_i, 0, 10000u * 4u, stream);

    // ---- attention phase (once) ----
    const int CONVB = (NN*SS*ZZ + 255)/256;   // 2500
    k_prep<<<17 + CONVB, 256, 0, stream>>>(Ws, Wd, F2w1, xw, xb, F2w2, F1w1, F1w2,
                                           ow1, ow2, zA, zG, inputs, dst,
                                           MT, G1f, G2f, c1f, c2f,
                                           W2b, F1w1b, F1w2b, ow1b, ow2b,
                                           zAb, zGb, xt, deg_i);
    k_scan<<<1, 1024, 0, stream>>>(deg_i, offsets, cursor);
    k_scatter<<<(NE + 255)/256, 256, 0, stream>>>(src, dst, cursor, src_by_pos);

    // ---- step 0 (attention fused with aggregation) ----
    k_attn_agg0<<<NN*SS, 64, 0, stream>>>(MT, zG, zGb, src_by_pos, offsets, xt,
                                          G1f, G2f, c1f, c2f, alpha, agg_b);
    k_node_mfma<<<(NN*SS + 63)/64, 256, 0, stream>>>(agg_b, zAb, W2b, F1w1b, F1w2b,
                                                     ow1b, ow2b, ob1, ob2, xt, out, 0);
    // ---- step 1 ----
    k_agg2<<<NN*SS, 64, 0, stream>>>(xt, G1f, G2f, c1f, c2f,
                                     src_by_pos, offsets, alpha, agg_b);
    k_node_mfma<<<(NN*SS + 63)/64, 256, 0, stream>>>(agg_b, zAb, W2b, F1w1b, F1w2b,
                                                     ow1b, ow2b, ob1, ob2, xt, out, 1);
}